// Round 5
// baseline (213.097 us; speedup 1.0000x reference)
//
#include <hip/hip_runtime.h>
#include <math.h>

#define BATCH   8
#define NPTS    4096
#define THREADS 512
#define WAVES   8
#define ROWS_PB 256          // rows per block (4 wave-pairs x 64)
#define CHUNK   512          // cols staged per half per step
#define NSTEP   4            // 2048 cols per half / CHUNK
#define NBLOCKS 256          // (4096/256) * 8 batches * 2 directions

#define LIK_F4      393216   // 8*192*1024 / 4
#define LIK_PER_BLK (LIK_F4 / NBLOCKS)   // 1536

typedef __attribute__((ext_vector_type(8)))  __bf16 bf16x8;
typedef __attribute__((ext_vector_type(16))) float  f32x16;

// feature vector [f0,f1,f2,f3,f4] duplicated into k=0..4 and k=8..12 via the
// lane-half mapping (lanes l and l+32 hold k-halves 0-7 / 8-15; identical
// content => MFMA result = 2*d2, halved in the epilogue).
__device__ inline bf16x8 packFeat(float f0, float f1, float f2, float f3, float f4) {
    bf16x8 r;
    r[0] = (__bf16)f0; r[1] = (__bf16)f1; r[2] = (__bf16)f2;
    r[3] = (__bf16)f3; r[4] = (__bf16)f4;
    r[5] = (__bf16)0.0f; r[6] = (__bf16)0.0f; r[7] = (__bf16)0.0f;
    return r;
}

// ---------------------------------------------------------------------------
// fused: chamfer NN-min via MFMA distance tiles (both directions via
// blockIdx.z) + per-block bpp slice. Block = 8 waves: wave-pair k owns rows
// [k*64, k*64+64), parity = col-half. D tile = A(rows feat) * B(cols feat)
// = 2*d2; running min in 2x f32x16; butterfly reduce at end.
// ---------------------------------------------------------------------------
__global__ __launch_bounds__(THREADS, 2) void fused_kernel(
    const float* __restrict__ Xin, const float* __restrict__ Yin,
    const float* __restrict__ lik,
    float* __restrict__ recPartial, float* __restrict__ bppPartial)
{
    const float* X; const float* Y;
    if (blockIdx.z == 0) { X = Xin; Y = Yin; }
    else                 { X = Yin; Y = Xin; }

    const int b = blockIdx.y;
    const int rowBase = (int)blockIdx.x * ROWS_PB;
    const int blk = ((int)blockIdx.z * gridDim.y + blockIdx.y) * gridDim.x + blockIdx.x;

    const int tid  = threadIdx.x;
    const int lane = tid & 63;
    const int w    = tid >> 6;
    const int pair = w >> 1;     // 0..3 : row group
    const int ph   = w & 1;      // 0/1  : col half
    const int li   = lane & 31;

    __shared__ bf16x8 yfeat[2][2][CHUNK];   // [buf][half][col] = 32 KB
    __shared__ float  cmb[2][ROWS_PB];
    __shared__ float  wr[WAVES], wb[WAVES];

    // ---- bpp slice (loads issue early, log2 overlaps MFMA via waves) ----
    float bs = 0.0f;
    {
        const float4* l4 = (const float4*)lik + (size_t)blk * LIK_PER_BLK;
        #pragma unroll
        for (int i = 0; i < LIK_PER_BLK / THREADS; ++i) {
            float4 v = l4[i * THREADS + tid];
            bs -= __log2f(v.x * v.y * v.z * v.w);   // min 1e-24, no underflow
        }
    }

    // ---- A fragments: rows rowBase + pair*64 + {li, li+32} ----
    bf16x8 a0, a1;
    {
        const float* p = X + ((size_t)b * NPTS + rowBase + pair * 64 + li) * 3;
        float x0 = p[0], x1 = p[1], x2 = p[2];
        a0 = packFeat(x0, x1, x2, fmaf(x0, x0, fmaf(x1, x1, x2 * x2)), 1.0f);
        const float* q = p + 32 * 3;
        float z0 = q[0], z1 = q[1], z2 = q[2];
        a1 = packFeat(z0, z1, z2, fmaf(z0, z0, fmaf(z1, z1, z2 * z2)), 1.0f);
    }

    f32x16 m0, m1, kZero;
    #pragma unroll
    for (int j = 0; j < 16; ++j) { m0[j] = 3.0e38f; m1[j] = 3.0e38f; kZero[j] = 0.0f; }

    // ---- staging: thread stages 2 cols of half sh per step ----
    const int sh = tid >> 8;
    const int sc = tid & 255;

    {   // prologue: step 0 -> buf 0
        const float* p0 = Y + ((size_t)b * NPTS + sh * 2048 + sc) * 3;
        float u0 = p0[0], u1 = p0[1], u2 = p0[2];
        const float* p1 = p0 + 256 * 3;
        float v0 = p1[0], v1 = p1[1], v2 = p1[2];
        yfeat[0][sh][sc]       = packFeat(-2.f*u0, -2.f*u1, -2.f*u2, 1.0f,
                                          fmaf(u0,u0,fmaf(u1,u1,u2*u2)));
        yfeat[0][sh][sc + 256] = packFeat(-2.f*v0, -2.f*v1, -2.f*v2, 1.0f,
                                          fmaf(v0,v0,fmaf(v1,v1,v2*v2)));
    }
    __syncthreads();

    int buf = 0;
    for (int s = 0; s < NSTEP; ++s) {
        // issue next chunk's global loads before compute (hide HBM latency)
        float u0, u1, u2, v0, v1, v2;
        if (s + 1 < NSTEP) {
            const float* p0 = Y + ((size_t)b * NPTS + sh * 2048 + (s + 1) * CHUNK + sc) * 3;
            u0 = p0[0]; u1 = p0[1]; u2 = p0[2];
            const float* p1 = p0 + 256 * 3;
            v0 = p1[0]; v1 = p1[1]; v2 = p1[2];
        }

        const bf16x8* yb = &yfeat[buf][ph][0];
        #pragma unroll
        for (int f = 0; f < 16; f += 2) {
            bf16x8 bA = yb[f * 32 + li];
            bf16x8 bB = yb[(f + 1) * 32 + li];
            f32x16 d0 = __builtin_amdgcn_mfma_f32_32x32x16_bf16(a0, bA, kZero, 0, 0, 0);
            f32x16 d1 = __builtin_amdgcn_mfma_f32_32x32x16_bf16(a1, bA, kZero, 0, 0, 0);
            f32x16 e0 = __builtin_amdgcn_mfma_f32_32x32x16_bf16(a0, bB, kZero, 0, 0, 0);
            f32x16 e1 = __builtin_amdgcn_mfma_f32_32x32x16_bf16(a1, bB, kZero, 0, 0, 0);
            #pragma unroll
            for (int j = 0; j < 16; ++j) {   // v_min3 fusion
                m0[j] = fminf(fminf(d0[j], e0[j]), m0[j]);
                m1[j] = fminf(fminf(d1[j], e1[j]), m1[j]);
            }
        }

        if (s + 1 < NSTEP) {
            yfeat[buf ^ 1][sh][sc]       = packFeat(-2.f*u0, -2.f*u1, -2.f*u2, 1.0f,
                                                    fmaf(u0,u0,fmaf(u1,u1,u2*u2)));
            yfeat[buf ^ 1][sh][sc + 256] = packFeat(-2.f*v0, -2.f*v1, -2.f*v2, 1.0f,
                                                    fmaf(v0,v0,fmaf(v1,v1,v2*v2)));
        }
        __syncthreads();
        buf ^= 1;
    }

    // ---- butterfly min over the 32 col-classes (within each lane-half) ----
    #pragma unroll
    for (int mask = 1; mask <= 16; mask <<= 1) {
        #pragma unroll
        for (int j = 0; j < 16; ++j) {
            m0[j] = fminf(m0[j], __shfl_xor(m0[j], mask, 64));
            m1[j] = fminf(m1[j], __shfl_xor(m1[j], mask, 64));
        }
    }

    // C/D layout: col=lane&31, row=(reg&3)+8*(reg>>2)+4*(lane>>5)
    if (li == 0) {
        int hi = lane >> 5;
        #pragma unroll
        for (int j = 0; j < 16; ++j) {
            int ri = (j & 3) + 8 * (j >> 2) + 4 * hi;
            cmb[ph][pair * 64 + ri]      = m0[j];
            cmb[ph][pair * 64 + 32 + ri] = m1[j];
        }
    }
    __syncthreads();

    // ---- block reduce: combine col-halves, halve (k-dup), clamp, sum ----
    float s = 0.0f;
    if (tid < ROWS_PB) {
        float mv = fminf(cmb[0][tid], cmb[1][tid]);
        s = fmaxf(0.5f * mv, 0.0f);
    }
    #pragma unroll
    for (int off = 32; off >= 1; off >>= 1) {
        s  += __shfl_down(s, off, 64);
        bs += __shfl_down(bs, off, 64);
    }
    if (lane == 0) { wr[w] = s; wb[w] = bs; }
    __syncthreads();
    if (tid == 0) {
        float rs = 0.0f, bb = 0.0f;
        #pragma unroll
        for (int j = 0; j < WAVES; ++j) { rs += wr[j]; bb += wb[j]; }
        recPartial[blk] = rs;
        bppPartial[blk] = bb;
    }
}

// ---------------------------------------------------------------------------
// final: sum the two 256-entry partial arrays; out = {rec+bpp, bpp, rec}
// ---------------------------------------------------------------------------
__global__ __launch_bounds__(256) void final_kernel(const float* __restrict__ recPartial,
                                                    const float* __restrict__ bppPartial,
                                                    float* __restrict__ out) {
    float sr = 0.0f, sb = 0.0f;
    for (int i = threadIdx.x; i < NBLOCKS; i += 256) {
        sr += recPartial[i];
        sb += bppPartial[i];
    }
    #pragma unroll
    for (int off = 32; off >= 1; off >>= 1) {
        sr += __shfl_down(sr, off, 64);
        sb += __shfl_down(sb, off, 64);
    }
    __shared__ float wrf[4], wbf[4];
    int lane = threadIdx.x & 63, w = threadIdx.x >> 6;
    if (lane == 0) { wrf[w] = sr; wbf[w] = sb; }
    __syncthreads();
    if (threadIdx.x == 0) {
        float rec = (wrf[0] + wrf[1] + wrf[2] + wrf[3]) * (1.0f / 32768.0f);
        float bpp = (wbf[0] + wbf[1] + wbf[2] + wbf[3]) * (1.0f / 32768.0f);
        out[0] = rec + bpp;
        out[1] = bpp;
        out[2] = rec;
    }
}

extern "C" void kernel_launch(void* const* d_in, const int* in_sizes, int n_in,
                              void* d_out, int out_size, void* d_ws, size_t ws_size,
                              hipStream_t stream) {
    const float* x_hat = (const float*)d_in[0];
    const float* pos   = (const float*)d_in[1];
    const float* lik   = (const float*)d_in[2];
    float* out = (float*)d_out;

    // workspace: [0,256) rec partials | [256,512) bpp partials (floats)
    float* recPartial = (float*)d_ws;
    float* bppPartial = recPartial + NBLOCKS;

    dim3 grid(NPTS / ROWS_PB, BATCH, 2);   // (16, 8, 2) = 256 blocks
    fused_kernel<<<grid, THREADS, 0, stream>>>(x_hat, pos, lik, recPartial, bppPartial);
    final_kernel<<<1, 256, 0, stream>>>(recPartial, bppPartial, out);
}

// Round 6
// 20.029 us; speedup vs baseline: 10.6396x; 10.6396x over previous
//
#include <hip/hip_runtime.h>
#include <math.h>

#define BATCH   8
#define NPTS    4096
#define THREADS 512
#define WAVES   8
#define ROWS_PB 128          // rows per block (4 wave row-groups x 32)
#define CHUNK   512          // cols staged per half per step
#define NSTEP   4            // 2048 cols per half / CHUNK
#define NBLOCKS 512          // (4096/128) * 8 batches * 2 directions

#define LIK_F4      393216   // 8*192*1024 / 4
#define LIK_PER_BLK (LIK_F4 / NBLOCKS)   // 768

typedef __attribute__((ext_vector_type(8)))  __bf16 bf16x8;
typedef __attribute__((ext_vector_type(16))) float  f32x16;

// feature vector [f0..f4] duplicated into both k-halves (lanes l / l+32 hold
// k=0..7 / 8..15 with identical content => MFMA result = 2*d2, halved at end).
__device__ inline bf16x8 packFeat(float f0, float f1, float f2, float f3, float f4) {
    bf16x8 r;
    r[0] = (__bf16)f0; r[1] = (__bf16)f1; r[2] = (__bf16)f2;
    r[3] = (__bf16)f3; r[4] = (__bf16)f4;
    r[5] = (__bf16)0.0f; r[6] = (__bf16)0.0f; r[7] = (__bf16)0.0f;
    return r;
}

// ---------------------------------------------------------------------------
// fused: chamfer NN-min via MFMA distance tiles (both directions via
// blockIdx.z) + per-block bpp slice. 8 waves: wave w owns rows
// [rowBase + (w>>1)*32, +32), col half (w&1). Inner body per B-frag pair:
// 2 MFMAs -> 16 v_min3 into ONE f32x16 accumulator (low register pressure,
// no spills). Y features double-buffered in LDS, loads issued early.
// ---------------------------------------------------------------------------
__global__ __launch_bounds__(THREADS, 2) void fused_kernel(
    const float* __restrict__ Xin, const float* __restrict__ Yin,
    const float* __restrict__ lik,
    float* __restrict__ recPartial, float* __restrict__ bppPartial)
{
    const float* X; const float* Y;
    if (blockIdx.z == 0) { X = Xin; Y = Yin; }
    else                 { X = Yin; Y = Xin; }

    const int b = blockIdx.y;
    const int rowBase = (int)blockIdx.x * ROWS_PB;
    const int blk = ((int)blockIdx.z * gridDim.y + blockIdx.y) * gridDim.x + blockIdx.x;

    const int tid  = threadIdx.x;
    const int lane = tid & 63;
    const int w    = tid >> 6;
    const int rg   = w >> 1;     // 0..3 : row group of 32
    const int ph   = w & 1;      // 0/1  : col half
    const int li   = lane & 31;
    const int hi   = lane >> 5;

    __shared__ bf16x8 yfeat[2][2][CHUNK];   // [buf][half][col] = 32 KB
    __shared__ float  cmb[2][ROWS_PB];
    __shared__ float  wr[WAVES], wb[WAVES];

    // ---- bpp slice ----
    float bs = 0.0f;
    {
        const float4* l4 = (const float4*)lik + (size_t)blk * LIK_PER_BLK;
        for (int i = tid; i < LIK_PER_BLK; i += THREADS) {
            float4 v = l4[i];
            bs -= __log2f(v.x * v.y * v.z * v.w);   // min 1e-24, no underflow
        }
    }

    // ---- A fragment: row = rowBase + rg*32 + li (both k-halves identical) ----
    bf16x8 a;
    {
        const float* p = X + ((size_t)b * NPTS + rowBase + rg * 32 + li) * 3;
        float x0 = p[0], x1 = p[1], x2 = p[2];
        a = packFeat(x0, x1, x2, fmaf(x0, x0, fmaf(x1, x1, x2 * x2)), 1.0f);
    }

    f32x16 m, kZero;
    #pragma unroll
    for (int j = 0; j < 16; ++j) { m[j] = 3.0e38f; kZero[j] = 0.0f; }

    // ---- staging: thread stages 2 cols of half sh per step ----
    const int sh = tid >> 8;
    const int sc = tid & 255;

    {   // prologue: step 0 -> buf 0
        const float* p0 = Y + ((size_t)b * NPTS + sh * 2048 + sc) * 3;
        float u0 = p0[0], u1 = p0[1], u2 = p0[2];
        const float* p1 = p0 + 256 * 3;
        float v0 = p1[0], v1 = p1[1], v2 = p1[2];
        yfeat[0][sh][sc]       = packFeat(-2.f*u0, -2.f*u1, -2.f*u2, 1.0f,
                                          fmaf(u0,u0,fmaf(u1,u1,u2*u2)));
        yfeat[0][sh][sc + 256] = packFeat(-2.f*v0, -2.f*v1, -2.f*v2, 1.0f,
                                          fmaf(v0,v0,fmaf(v1,v1,v2*v2)));
    }
    __syncthreads();

    int buf = 0;
    for (int s = 0; s < NSTEP; ++s) {
        // issue next chunk's global loads before compute (hide HBM latency)
        float u0, u1, u2, v0, v1, v2;
        if (s + 1 < NSTEP) {
            const float* p0 = Y + ((size_t)b * NPTS + sh * 2048 + (s + 1) * CHUNK + sc) * 3;
            u0 = p0[0]; u1 = p0[1]; u2 = p0[2];
            const float* p1 = p0 + 256 * 3;
            v0 = p1[0]; v1 = p1[1]; v2 = p1[2];
        }

        const bf16x8* yb = &yfeat[buf][ph][0];
        #pragma unroll 2
        for (int f = 0; f < 16; f += 2) {
            bf16x8 bA = yb[f * 32 + li];
            bf16x8 bB = yb[(f + 1) * 32 + li];
            f32x16 d = __builtin_amdgcn_mfma_f32_32x32x16_bf16(a, bA, kZero, 0, 0, 0);
            f32x16 e = __builtin_amdgcn_mfma_f32_32x32x16_bf16(a, bB, kZero, 0, 0, 0);
            #pragma unroll
            for (int j = 0; j < 16; ++j)        // v_min3 fusion
                m[j] = fminf(fminf(d[j], e[j]), m[j]);
        }

        if (s + 1 < NSTEP) {
            yfeat[buf ^ 1][sh][sc]       = packFeat(-2.f*u0, -2.f*u1, -2.f*u2, 1.0f,
                                                    fmaf(u0,u0,fmaf(u1,u1,u2*u2)));
            yfeat[buf ^ 1][sh][sc + 256] = packFeat(-2.f*v0, -2.f*v1, -2.f*v2, 1.0f,
                                                    fmaf(v0,v0,fmaf(v1,v1,v2*v2)));
        }
        __syncthreads();
        buf ^= 1;
    }

    // ---- butterfly min over the 32 col-classes (within each lane-half) ----
    #pragma unroll
    for (int mask = 1; mask <= 16; mask <<= 1)
        #pragma unroll
        for (int j = 0; j < 16; ++j)
            m[j] = fminf(m[j], __shfl_xor(m[j], mask, 64));

    // C/D layout: col=lane&31, row=(reg&3)+8*(reg>>2)+4*(lane>>5)
    if (li == 0) {
        #pragma unroll
        for (int j = 0; j < 16; ++j) {
            int ri = (j & 3) + 8 * (j >> 2) + 4 * hi;
            cmb[ph][rg * 32 + ri] = m[j];
        }
    }
    __syncthreads();

    // ---- block reduce: combine col-halves, halve (k-dup), clamp, sum ----
    float s = 0.0f;
    if (tid < ROWS_PB) {
        float mv = fminf(cmb[0][tid], cmb[1][tid]);
        s = fmaxf(0.5f * mv, 0.0f);
    }
    #pragma unroll
    for (int off = 32; off >= 1; off >>= 1) {
        s  += __shfl_down(s, off, 64);
        bs += __shfl_down(bs, off, 64);
    }
    if (lane == 0) { wr[w] = s; wb[w] = bs; }
    __syncthreads();
    if (tid == 0) {
        float rs = 0.0f, bb = 0.0f;
        #pragma unroll
        for (int j = 0; j < WAVES; ++j) { rs += wr[j]; bb += wb[j]; }
        recPartial[blk] = rs;
        bppPartial[blk] = bb;
    }
}

// ---------------------------------------------------------------------------
// final: sum the two 512-entry partial arrays; out = {rec+bpp, bpp, rec}
// ---------------------------------------------------------------------------
__global__ __launch_bounds__(256) void final_kernel(const float* __restrict__ recPartial,
                                                    const float* __restrict__ bppPartial,
                                                    float* __restrict__ out) {
    float sr = 0.0f, sb = 0.0f;
    for (int i = threadIdx.x; i < NBLOCKS; i += 256) {
        sr += recPartial[i];
        sb += bppPartial[i];
    }
    #pragma unroll
    for (int off = 32; off >= 1; off >>= 1) {
        sr += __shfl_down(sr, off, 64);
        sb += __shfl_down(sb, off, 64);
    }
    __shared__ float wrf[4], wbf[4];
    int lane = threadIdx.x & 63, w = threadIdx.x >> 6;
    if (lane == 0) { wrf[w] = sr; wbf[w] = sb; }
    __syncthreads();
    if (threadIdx.x == 0) {
        float rec = (wrf[0] + wrf[1] + wrf[2] + wrf[3]) * (1.0f / 32768.0f);
        float bpp = (wbf[0] + wbf[1] + wbf[2] + wbf[3]) * (1.0f / 32768.0f);
        out[0] = rec + bpp;
        out[1] = bpp;
        out[2] = rec;
    }
}

extern "C" void kernel_launch(void* const* d_in, const int* in_sizes, int n_in,
                              void* d_out, int out_size, void* d_ws, size_t ws_size,
                              hipStream_t stream) {
    const float* x_hat = (const float*)d_in[0];
    const float* pos   = (const float*)d_in[1];
    const float* lik   = (const float*)d_in[2];
    float* out = (float*)d_out;

    // workspace: [0,512) rec partials | [512,1024) bpp partials (floats)
    float* recPartial = (float*)d_ws;
    float* bppPartial = recPartial + NBLOCKS;

    dim3 grid(NPTS / ROWS_PB, BATCH, 2);   // (32, 8, 2) = 512 blocks
    fused_kernel<<<grid, THREADS, 0, stream>>>(x_hat, pos, lik, recPartial, bppPartial);
    final_kernel<<<1, 256, 0, stream>>>(recPartial, bppPartial, out);
}